// Round 3
// baseline (305.031 us; speedup 1.0000x reference)
//
#include <hip/hip_runtime.h>

// Autoregressive GRU decoder, B=32768, H=32, T=128, fp32 in/out.
// MFMA-based: per step gates[128] = Wf[128x32] . h[32 x 16elem] via 8 tiles of
// v_mfma_f32_16x16x32_bf16, with each fp32 operand split EXACTLY into 3
// truncated bf16 terms (a = ah+am+al, bit-masked). 6 MFMAs/tile keep all cross
// terms >= 2^-24 -> fp32-equivalent accuracy (dropped terms ~2*2^-24 rel).
// Weights fused for t>=1 (x==h so r/z use W_ih+W_hh); weight fragments live in
// VGPRs across all steps (zero weight traffic in loop). Gate combine is
// lane-local thanks to C layout (col=lane&15, row=(lane>>4)*4+reg). h_new ->
// next-step B fragment redistribution via tiny XOR-swizzled LDS (4 ds ops/step,
// 2-way conflicts = free). 16 elements/wave, 2048 waves = 2/SIMD exactly.

typedef __attribute__((ext_vector_type(8)))  short short8;   // 8 bf16 = 4 VGPRs
typedef __attribute__((ext_vector_type(4)))  float f32x4;

struct F3 { short8 h, m, l; };                               // 3-way split fragment

__device__ __forceinline__ void ldrow8(const float* p, float f[8]) {
    f32x4 a = *(const f32x4*)p;
    f32x4 b = *(const f32x4*)(p + 4);
    f[0]=a[0]; f[1]=a[1]; f[2]=a[2]; f[3]=a[3];
    f[4]=b[0]; f[5]=b[1]; f[6]=b[2]; f[7]=b[3];
}

// exact 3-term bf16 split of 8 fp32, packed low-k-first into bf16x2 dwords
__device__ __forceinline__ F3 split8(const float f[8]) {
    unsigned H[8], M[8], L[8];
    #pragma unroll
    for (int i = 0; i < 8; ++i) {
        unsigned a = __float_as_uint(f[i]);
        unsigned h = a & 0xffff0000u;
        float    t = f[i] - __uint_as_float(h);
        unsigned m = __float_as_uint(t) & 0xffff0000u;
        float    u = t - __uint_as_float(m);
        unsigned l = __float_as_uint(u) & 0xffff0000u;      // remainder exact
        H[i] = h; M[i] = m; L[i] = l;
    }
    union { unsigned u[4]; short8 s; } uh, um, ul;
    #pragma unroll
    for (int p = 0; p < 4; ++p) {                           // dword p = (k=2p+1, k=2p)
        uh.u[p] = __builtin_amdgcn_perm(H[2*p+1], H[2*p], 0x07060302u);
        um.u[p] = __builtin_amdgcn_perm(M[2*p+1], M[2*p], 0x07060302u);
        ul.u[p] = __builtin_amdgcn_perm(L[2*p+1], L[2*p], 0x07060302u);
    }
    F3 r; r.h = uh.s; r.m = um.s; r.l = ul.s; return r;
}

#define MFMA(a,b,c) __builtin_amdgcn_mfma_f32_16x16x32_bf16((a),(b),(c),0,0,0)

// 6-term product chain, small terms first; c0 = bias (resets acc every step)
__device__ __forceinline__ f32x4 mm6(const F3& A, const F3& B, f32x4 c) {
    c = MFMA(A.h, B.l, c);
    c = MFMA(A.l, B.h, c);
    c = MFMA(A.m, B.m, c);
    c = MFMA(A.h, B.m, c);
    c = MFMA(A.m, B.h, c);
    c = MFMA(A.h, B.h, c);
    return c;
}

__device__ __forceinline__ float rcp_nr(float x) {
    float r = __builtin_amdgcn_rcpf(x);
    return r * fmaf(-x, r, 2.f);
}
__device__ __forceinline__ float sigm_(float x) {
    x = __builtin_amdgcn_fmed3f(x, -60.f, 60.f);
    return rcp_nr(1.f + __expf(-x));
}
__device__ __forceinline__ float tanh_(float x) {
    x = __builtin_amdgcn_fmed3f(x, -30.f, 30.f);
    return fmaf(-2.f, rcp_nr(__expf(2.f * x) + 1.f), 1.f);
}
__device__ __forceinline__ float comb_(float ar, float az, float an_, float ahn, float hp) {
    float rr = sigm_(ar);
    float zz = sigm_(az);
    float nn = tanh_(fmaf(rr, ahn, an_));
    return fmaf(zz, hp - nn, nn);
}

__global__ __launch_bounds__(256, 2)
void gru_mfma(const float* __restrict__ in_data, const float* __restrict__ hidden,
              const float* __restrict__ W_ih,   const float* __restrict__ W_hh,
              const float* __restrict__ b_ih,   const float* __restrict__ b_hh,
              const float* __restrict__ W_out,  const float* __restrict__ b_out,
              float* __restrict__ out, int B, int T)
{
    // per-wave h exchange scratch: [wave][elem][comp], XOR-swizzled granules
    __shared__ __align__(16) float hxch[4][16][32];

    const int tid  = threadIdx.x;
    const int lane = tid & 63, wv = tid >> 6;
    const int n    = lane & 15;          // MFMA col = batch element; also A row
    const int g    = lane >> 4;          // k-group
    const int k0   = g * 8;              // this lane's B k-range
    const int c_lo = g * 4;              // this lane's C row base (+reg)
    const long e   = (long)blockIdx.x * 64 + wv * 16 + n;   // batch element
    float* hb      = &hxch[wv][0][0];
    const int swz  = (n & 7) * 4;        // granule XOR swizzle per element

    // ---- resident per-lane constants ----
    f32x4 bC[8];                          // bias in C layout, per tile
    #pragma unroll
    for (int tt = 0; tt < 8; ++tt) {
        #pragma unroll
        for (int r = 0; r < 4; ++r) {
            int c = c_lo + r;
            float v;
            if      (tt < 4) { int i = tt * 16 + c;            v = b_ih[i] + b_hh[i]; }
            else if (tt < 6) { int i = 64 + (tt - 4) * 16 + c; v = b_ih[i]; }
            else             { int i = 64 + (tt - 6) * 16 + c; v = b_hh[i]; }
            bC[tt][r] = v;
        }
    }
    float wlo[4], whi[4], hplo[4], hphi[4];
    #pragma unroll
    for (int r = 0; r < 4; ++r) { wlo[r] = W_out[c_lo + r]; whi[r] = W_out[16 + c_lo + r]; }
    {   f32x4 a = *(const f32x4*)(hidden + e * 32 + c_lo);
        f32x4 b = *(const f32x4*)(hidden + e * 32 + 16 + c_lo);
        #pragma unroll
        for (int r = 0; r < 4; ++r) { hplo[r] = a[r]; hphi[r] = b[r]; }
    }
    const float boutv = b_out[0];

    // ---- initial B fragments: x (in_data) and h (hidden) ----
    F3 Bx, Bv;
    { float f[8]; ldrow8(in_data + e * 32 + k0, f); Bx = split8(f); }
    { float f[8]; ldrow8(hidden  + e * 32 + k0, f); Bv = split8(f); }

    F3 A[8];
    f32x4 C[8];

    // ---- step 0, x-phase: gi = W_ih . x (+bias), tiles 0..5 ----
    #pragma unroll
    for (int rt = 0; rt < 6; ++rt) {
        float f[8]; ldrow8(W_ih + (rt * 16 + n) * 32 + k0, f);
        A[rt] = split8(f);
    }
    #pragma unroll
    for (int rt = 0; rt < 6; ++rt) C[rt] = mm6(A[rt], Bx, bC[rt]);

    // ---- step 0, h-phase: += W_hh . h ; h_n tiles -> C6,C7 ----
    #pragma unroll
    for (int rt = 0; rt < 6; ++rt) {
        float f[8]; ldrow8(W_hh + (rt * 16 + n) * 32 + k0, f);
        A[rt] = split8(f);
    }
    #pragma unroll
    for (int rt = 0; rt < 4; ++rt) C[rt] = mm6(A[rt], Bv, C[rt]);        // r,z accumulate
    C[6] = mm6(A[4], Bv, bC[6]);                                         // h_n
    C[7] = mm6(A[5], Bv, bC[7]);

    // ---- fused weights for t>=1: rows 0..63 = Wih+Whh (r,z); 64..95 i_n; 96..127 h_n
    #pragma unroll
    for (int rt = 0; rt < 8; ++rt) {
        float f[8];
        if (rt < 4) {
            float f2[8];
            ldrow8(W_ih + (rt * 16 + n) * 32 + k0, f);
            ldrow8(W_hh + (rt * 16 + n) * 32 + k0, f2);
            #pragma unroll
            for (int i = 0; i < 8; ++i) f[i] += f2[i];
        } else if (rt < 6) {
            ldrow8(W_ih + (64 + (rt - 4) * 16 + n) * 32 + k0, f);
        } else {
            ldrow8(W_hh + (64 + (rt - 6) * 16 + n) * 32 + k0, f);
        }
        A[rt] = split8(f);
    }

    // ---- main sequential loop ----
    #pragma unroll 1
    for (int t = 0; t < T; ++t) {
        // combine: gates (C tiles) + h_prev -> h_new (lane-local), y partial
        float hl[4], hh2[4], yp = 0.f;
        #pragma unroll
        for (int r = 0; r < 4; ++r) {
            hl[r]  = comb_(C[0][r], C[2][r], C[4][r], C[6][r], hplo[r]);
            hh2[r] = comb_(C[1][r], C[3][r], C[5][r], C[7][r], hphi[r]);
            yp = fmaf(wlo[r], hl[r], yp);
            yp = fmaf(whi[r], hh2[r], yp);
            hplo[r] = hl[r]; hphi[r] = hh2[r];
        }
        yp += __shfl_xor(yp, 16);
        yp += __shfl_xor(yp, 32);
        if (lane < 16) out[e * T + t] = yp + boutv;
        if (t == T - 1) break;

        // redistribute h_new (C layout -> B layout) through swizzled LDS
        {
            f32x4 w0, w1;
            #pragma unroll
            for (int r = 0; r < 4; ++r) { w0[r] = hl[r]; w1[r] = hh2[r]; }
            *(f32x4*)(hb + n * 32 + ((c_lo)      ^ swz)) = w0;
            *(f32x4*)(hb + n * 32 + ((16 + c_lo) ^ swz)) = w1;
            f32x4 r0 = *(const f32x4*)(hb + n * 32 + ((k0)     ^ swz));
            f32x4 r1 = *(const f32x4*)(hb + n * 32 + ((k0 + 4) ^ swz));
            float f[8];
            #pragma unroll
            for (int r = 0; r < 4; ++r) { f[r] = r0[r]; f[4 + r] = r1[r]; }
            Bv = split8(f);
        }

        // next-step gates: C = bias + Wf . h_new   (acc reset via bias as C-in)
        #pragma unroll
        for (int rt = 0; rt < 8; ++rt) C[rt] = mm6(A[rt], Bv, bC[rt]);
    }
}

extern "C" void kernel_launch(void* const* d_in, const int* in_sizes, int n_in,
                              void* d_out, int out_size, void* d_ws, size_t ws_size,
                              hipStream_t stream) {
    const float* in_data = (const float*)d_in[0];
    const float* hidden  = (const float*)d_in[1];
    const float* W_ih    = (const float*)d_in[2];
    const float* W_hh    = (const float*)d_in[3];
    const float* b_ih    = (const float*)d_in[4];
    const float* b_hh    = (const float*)d_in[5];
    const float* W_out   = (const float*)d_in[6];
    const float* b_out   = (const float*)d_in[7];
    float* out = (float*)d_out;

    const int B = in_sizes[0] / 32;       // 32768
    const int T = out_size / B;           // 128
    const int blocks = B / 64;            // 16 elems/wave * 4 waves/block

    gru_mfma<<<blocks, 256, 0, stream>>>(in_data, hidden, W_ih, W_hh,
                                         b_ih, b_hh, W_out, b_out, out, B, T);
}

// Round 5
// 298.754 us; speedup vs baseline: 1.0210x; 1.0210x over previous
//
#include <hip/hip_runtime.h>

// Autoregressive GRU decoder, B=32768, H=32, T=128, fp32 in/out.
// MFMA 16x16x32 bf16 with EXACT 3-way bf16 split (6 MFMAs/tile, fp32-equiv).
// Gate-matrix rows are PERMUTED so each lane's MFMA C-output components
// (C rows 4g+r of lo/hi tiles) are exactly the k-slice (8g..8g+7) that the
// same lane supplies as the B fragment next step. The h feedback is therefore
// fully lane-local: no LDS, no cross-lane traffic except 2 shfl_xor for the
// scalar y reduction. h-trajectory arithmetic is bit-identical to the round-3
// kernel that passed (absmax 9.8e-4); only y's reduction order changes (~1 ulp).
// Permutation: lo tile C-row p <-> weight row 8*(p>>2)+(p&3); hi tile: +4.

typedef __attribute__((ext_vector_type(8)))  short short8;   // 8 bf16 = 4 VGPRs
typedef __attribute__((ext_vector_type(4)))  float f32x4;

struct F3 { short8 h, m, l; };                               // 3-way split fragment

__device__ __forceinline__ void ldrow8(const float* p, float f[8]) {
    f32x4 a = *(const f32x4*)p;
    f32x4 b = *(const f32x4*)(p + 4);
    f[0]=a[0]; f[1]=a[1]; f[2]=a[2]; f[3]=a[3];
    f[4]=b[0]; f[5]=b[1]; f[6]=b[2]; f[7]=b[3];
}

// exact 3-term bf16 split of 8 fp32, packed low-k-first into bf16x2 dwords
__device__ __forceinline__ F3 split8(const float f[8]) {
    unsigned H[8], M[8], L[8];
    #pragma unroll
    for (int i = 0; i < 8; ++i) {
        unsigned a = __float_as_uint(f[i]);
        unsigned h = a & 0xffff0000u;
        float    t = f[i] - __uint_as_float(h);
        unsigned m = __float_as_uint(t) & 0xffff0000u;
        float    u = t - __uint_as_float(m);
        unsigned l = __float_as_uint(u) & 0xffff0000u;      // remainder exact
        H[i] = h; M[i] = m; L[i] = l;
    }
    union { unsigned u[4]; short8 s; } uh, um, ul;
    #pragma unroll
    for (int p = 0; p < 4; ++p) {                           // dword p = (k=2p+1, k=2p)
        uh.u[p] = __builtin_amdgcn_perm(H[2*p+1], H[2*p], 0x07060302u);
        um.u[p] = __builtin_amdgcn_perm(M[2*p+1], M[2*p], 0x07060302u);
        ul.u[p] = __builtin_amdgcn_perm(L[2*p+1], L[2*p], 0x07060302u);
    }
    F3 r; r.h = uh.s; r.m = um.s; r.l = ul.s; return r;
}

#define MFMA(a,b,c) __builtin_amdgcn_mfma_f32_16x16x32_bf16((a),(b),(c),0,0,0)

// 6-term product chain, small terms first; c0 = bias (resets acc every step)
__device__ __forceinline__ f32x4 mm6(const F3& A, const F3& B, f32x4 c) {
    c = MFMA(A.h, B.l, c);
    c = MFMA(A.l, B.h, c);
    c = MFMA(A.m, B.m, c);
    c = MFMA(A.h, B.m, c);
    c = MFMA(A.m, B.h, c);
    c = MFMA(A.h, B.h, c);
    return c;
}

__device__ __forceinline__ float rcp_nr(float x) {
    float r = __builtin_amdgcn_rcpf(x);
    return r * fmaf(-x, r, 2.f);
}
__device__ __forceinline__ float sigm_(float x) {
    x = __builtin_amdgcn_fmed3f(x, -60.f, 60.f);
    return rcp_nr(1.f + __expf(-x));
}
__device__ __forceinline__ float tanh_(float x) {
    x = __builtin_amdgcn_fmed3f(x, -30.f, 30.f);
    return fmaf(-2.f, rcp_nr(__expf(2.f * x) + 1.f), 1.f);
}
__device__ __forceinline__ float comb_(float ar, float az, float an_, float ahn, float hp) {
    float rr = sigm_(ar);
    float zz = sigm_(az);
    float nn = tanh_(fmaf(rr, ahn, an_));
    return fmaf(zz, hp - nn, nn);
}

__global__ __launch_bounds__(256, 2)
void gru_mfma(const float* __restrict__ in_data, const float* __restrict__ hidden,
              const float* __restrict__ W_ih,   const float* __restrict__ W_hh,
              const float* __restrict__ b_ih,   const float* __restrict__ b_hh,
              const float* __restrict__ W_out,  const float* __restrict__ b_out,
              float* __restrict__ out, int B, int T)
{
    const int tid  = threadIdx.x;
    const int lane = tid & 63, wv = tid >> 6;
    const int n    = lane & 15;          // MFMA col = batch element; also A row
    const int g    = lane >> 4;          // k-group: this lane's B k-slice 8g..8g+7
    const int k0   = g * 8;
    const long e   = (long)blockIdx.x * 64 + wv * 16 + n;   // batch element

    // permuted weight-row for this lane's A row (= row n of each tile):
    const int rlo = 8 * (n >> 2) + (n & 3);   // lo tile row offset within a gate-set
    const int rhi = rlo + 4;                  // hi tile

    // ---- resident per-lane constants ----
    // biases in C layout: lane holds C rows 4g+r -> comp 8g+r (lo) / 8g+4+r (hi)
    f32x4 bC[8];
    #pragma unroll
    for (int p = 0; p < 2; ++p) {
        #pragma unroll
        for (int r = 0; r < 4; ++r) {
            const int c = 8 * g + 4 * p + r;             // comp 0..31 within gate-set
            bC[0 + p][r] = b_ih[c]      + b_hh[c];       // r-gate (fused bias)
            bC[2 + p][r] = b_ih[32 + c] + b_hh[32 + c];  // z-gate
            bC[4 + p][r] = b_ih[64 + c];                 // i_n
            bC[6 + p][r] = b_hh[64 + c];                 // h_n
        }
    }
    float wl[4], wh[4];
    #pragma unroll
    for (int r = 0; r < 4; ++r) { wl[r] = W_out[8*g + r]; wh[r] = W_out[8*g + 4 + r]; }
    const float boutv = b_out[0];
    float* const op = out + e * (long)T;

    // ---- initial h (k-slice = this lane's own comps) and x fragments ----
    float hp[8];
    F3 Bv, Bx;
    {
        float f[8]; ldrow8(hidden + e * 32 + k0, f);
        #pragma unroll
        for (int i = 0; i < 8; ++i) hp[i] = f[i];
        Bv = split8(f);
        float fx[8]; ldrow8(in_data + e * 32 + k0, fx);
        Bx = split8(fx);
    }

    F3 A[8];
    f32x4 C[8];

    // ---- step 0, x-phase: W_ih tiles {r,z,n} x {lo,hi}, permuted rows ----
    #pragma unroll
    for (int gs = 0; gs < 3; ++gs) {
        float fl[8], fh[8];
        ldrow8(W_ih + (gs * 32 + rlo) * 32 + k0, fl);
        ldrow8(W_ih + (gs * 32 + rhi) * 32 + k0, fh);
        A[2*gs] = split8(fl); A[2*gs+1] = split8(fh);
    }
    #pragma unroll
    for (int rt = 0; rt < 6; ++rt) C[rt] = mm6(A[rt], Bx, bC[rt]);

    // ---- step 0, h-phase: W_hh; r,z accumulate; h_n -> C6,C7 ----
    #pragma unroll
    for (int gs = 0; gs < 3; ++gs) {
        float fl[8], fh[8];
        ldrow8(W_hh + (gs * 32 + rlo) * 32 + k0, fl);
        ldrow8(W_hh + (gs * 32 + rhi) * 32 + k0, fh);
        A[2*gs] = split8(fl); A[2*gs+1] = split8(fh);
    }
    #pragma unroll
    for (int rt = 0; rt < 4; ++rt) C[rt] = mm6(A[rt], Bv, C[rt]);
    C[6] = mm6(A[4], Bv, bC[6]);
    C[7] = mm6(A[5], Bv, bC[7]);

    // ---- fused weights for t>=1: r,z = W_ih+W_hh; i_n = W_ih; h_n = W_hh ----
    #pragma unroll
    for (int gs = 0; gs < 2; ++gs) {                     // r, z combined
        float fl[8], fh[8], g2[8];
        ldrow8(W_ih + (gs * 32 + rlo) * 32 + k0, fl);
        ldrow8(W_hh + (gs * 32 + rlo) * 32 + k0, g2);
        #pragma unroll
        for (int i = 0; i < 8; ++i) fl[i] += g2[i];
        ldrow8(W_ih + (gs * 32 + rhi) * 32 + k0, fh);
        ldrow8(W_hh + (gs * 32 + rhi) * 32 + k0, g2);
        #pragma unroll
        for (int i = 0; i < 8; ++i) fh[i] += g2[i];
        A[2*gs] = split8(fl); A[2*gs+1] = split8(fh);
    }
    {
        float fl[8], fh[8];
        ldrow8(W_ih + (64 + rlo) * 32 + k0, fl);
        ldrow8(W_ih + (64 + rhi) * 32 + k0, fh);
        A[4] = split8(fl); A[5] = split8(fh);
        ldrow8(W_hh + (64 + rlo) * 32 + k0, fl);
        ldrow8(W_hh + (64 + rhi) * 32 + k0, fh);
        A[6] = split8(fl); A[7] = split8(fh);
    }

    // ---- main sequential loop: fully lane-local h feedback ----
    #pragma unroll 1
    for (int t = 0; t < T; ++t) {
        float h8[8], yp = 0.f;
        #pragma unroll
        for (int r = 0; r < 4; ++r) {
            float a  = comb_(C[0][r], C[2][r], C[4][r], C[6][r], hp[r]);      // comp 8g+r
            float b2 = comb_(C[1][r], C[3][r], C[5][r], C[7][r], hp[4 + r]);  // comp 8g+4+r
            yp = fmaf(wl[r], a,  yp);
            yp = fmaf(wh[r], b2, yp);
            h8[r] = a; h8[4 + r] = b2;
            hp[r] = a; hp[4 + r] = b2;
        }
        yp += __shfl_xor(yp, 16);
        yp += __shfl_xor(yp, 32);
        if (lane < 16) op[t] = yp + boutv;
        if (t == T - 1) break;

        Bv = split8(h8);                                  // own comps ARE the k-slice
        #pragma unroll
        for (int rt = 0; rt < 8; ++rt) C[rt] = mm6(A[rt], Bv, bC[rt]);
    }
}

extern "C" void kernel_launch(void* const* d_in, const int* in_sizes, int n_in,
                              void* d_out, int out_size, void* d_ws, size_t ws_size,
                              hipStream_t stream) {
    const float* in_data = (const float*)d_in[0];
    const float* hidden  = (const float*)d_in[1];
    const float* W_ih    = (const float*)d_in[2];
    const float* W_hh    = (const float*)d_in[3];
    const float* b_ih    = (const float*)d_in[4];
    const float* b_hh    = (const float*)d_in[5];
    const float* W_out   = (const float*)d_in[6];
    const float* b_out   = (const float*)d_in[7];
    float* out = (float*)d_out;

    const int B = in_sizes[0] / 32;       // 32768
    const int T = out_size / B;           // 128
    const int blocks = B / 64;            // 16 elems/wave * 4 waves/block

    gru_mfma<<<blocks, 256, 0, stream>>>(in_data, hidden, W_ih, W_hh,
                                         b_ih, b_hh, W_out, b_out, out, B, T);
}

// Round 6
// 290.108 us; speedup vs baseline: 1.0514x; 1.0298x over previous
//
#include <hip/hip_runtime.h>

// Autoregressive GRU decoder, B=32768, H=32, T=128, fp32 in/out.
// MFMA 16x16x32 bf16, EXACT 3-way bf16 split (6 MFMAs/tile, fp32-equiv).
// Row-permuted weights make h-feedback fully lane-local (round-4/5 design).
// ROUND-6 CHANGES:
//  (1) TWO element-groups per wave (A=cols 0-15, B=16-31) sharing the resident
//      weight fragments. Rotated body: MFMA_A ; combineB ; MFMA_B ; combineA'.
//      Every MFMA burst is adjacent to an INDEPENDENT combine -> scheduler can
//      interleave VALU into MFMA back-pressure gaps (deterministic overlap;
//      r5 measured MfmaUtil 34% + VALUBusy 60% = serialized pipes).
//  (2) exp2-folding: r/z weights+biases pre-scaled by -log2e, n-gate by
//      +2*log2e -> activations use raw v_exp_f32, no arg muls/negations.
//  (3) clamps dropped (preacts provably bounded ~|30|; exp2 finite, NR-safe).
// 1024 blocks x 64 threads = 1024 waves = 1/SIMD exactly; no LDS.

typedef __attribute__((ext_vector_type(8)))  short short8;   // 8 bf16 = 4 VGPRs
typedef __attribute__((ext_vector_type(4)))  float f32x4;

struct F3 { short8 h, m, l; };                               // 3-way split fragment

__device__ __forceinline__ void ldrow8(const float* p, float f[8]) {
    f32x4 a = *(const f32x4*)p;
    f32x4 b = *(const f32x4*)(p + 4);
    f[0]=a[0]; f[1]=a[1]; f[2]=a[2]; f[3]=a[3];
    f[4]=b[0]; f[5]=b[1]; f[6]=b[2]; f[7]=b[3];
}
__device__ __forceinline__ void ldrow8s(const float* p, float f[8], float s) {
    ldrow8(p, f);
    #pragma unroll
    for (int i = 0; i < 8; ++i) f[i] *= s;
}

// exact 3-term bf16 split of 8 fp32, packed low-k-first into bf16x2 dwords
__device__ __forceinline__ F3 split8(const float f[8]) {
    unsigned H[8], M[8], L[8];
    #pragma unroll
    for (int i = 0; i < 8; ++i) {
        unsigned a = __float_as_uint(f[i]);
        unsigned h = a & 0xffff0000u;
        float    t = f[i] - __uint_as_float(h);
        unsigned m = __float_as_uint(t) & 0xffff0000u;
        float    u = t - __uint_as_float(m);
        unsigned l = __float_as_uint(u) & 0xffff0000u;      // remainder exact
        H[i] = h; M[i] = m; L[i] = l;
    }
    union { unsigned u[4]; short8 s; } uh, um, ul;
    #pragma unroll
    for (int p = 0; p < 4; ++p) {                           // dword p = (k=2p+1, k=2p)
        uh.u[p] = __builtin_amdgcn_perm(H[2*p+1], H[2*p], 0x07060302u);
        um.u[p] = __builtin_amdgcn_perm(M[2*p+1], M[2*p], 0x07060302u);
        ul.u[p] = __builtin_amdgcn_perm(L[2*p+1], L[2*p], 0x07060302u);
    }
    F3 r; r.h = uh.s; r.m = um.s; r.l = ul.s; return r;
}

#define MFMA(a,b,c) __builtin_amdgcn_mfma_f32_16x16x32_bf16((a),(b),(c),0,0,0)

// 6-term product chain, small terms first; c0 = bias (resets acc every step)
__device__ __forceinline__ f32x4 mm6(const F3& A, const F3& B, f32x4 c) {
    c = MFMA(A.h, B.l, c);
    c = MFMA(A.l, B.h, c);
    c = MFMA(A.m, B.m, c);
    c = MFMA(A.h, B.m, c);
    c = MFMA(A.m, B.h, c);
    c = MFMA(A.h, B.h, c);
    return c;
}

__device__ __forceinline__ void mfma8(const F3 A[8], const F3& Bv,
                                      const f32x4 bC[8], f32x4 C[8]) {
    #pragma unroll
    for (int rt = 0; rt < 8; ++rt) C[rt] = mm6(A[rt], Bv, bC[rt]);
}

__device__ __forceinline__ float rcp_nr(float x) {
    float r = __builtin_amdgcn_rcpf(x);
    return r * fmaf(-x, r, 2.f);
}
// inputs pre-scaled: arN,azN = -log2e * preact ; anS,ahnS = 2*log2e * preact
__device__ __forceinline__ float comb_(float arN, float azN, float anS, float ahnS, float hp) {
    float rr = rcp_nr(1.f + __builtin_amdgcn_exp2f(arN));
    float zz = rcp_nr(1.f + __builtin_amdgcn_exp2f(azN));
    float q  = rcp_nr(__builtin_amdgcn_exp2f(fmaf(rr, ahnS, anS)) + 1.f);
    float nn = fmaf(-2.f, q, 1.f);                           // tanh
    return fmaf(zz, hp - nn, nn);
}

// one group's combine: gates->h_new (lane-local), y emit, refresh B fragment
__device__ __forceinline__ void combineG(const f32x4 C[8], float hp[8], F3& Bv,
                                         const float wl[4], const float wh[4],
                                         float boutv, float* op, int t, bool st) {
    float h8[8], yp = 0.f;
    #pragma unroll
    for (int r = 0; r < 4; ++r) {
        float a  = comb_(C[0][r], C[2][r], C[4][r], C[6][r], hp[r]);      // comp 8g+r
        float b2 = comb_(C[1][r], C[3][r], C[5][r], C[7][r], hp[4 + r]);  // comp 8g+4+r
        yp = fmaf(wl[r], a, yp);
        yp = fmaf(wh[r], b2, yp);
        h8[r] = a; h8[4 + r] = b2;
        hp[r] = a; hp[4 + r] = b2;
    }
    yp += __shfl_xor(yp, 16);
    yp += __shfl_xor(yp, 32);
    if (st) op[t] = yp + boutv;
    Bv = split8(h8);
}

__global__ __launch_bounds__(64, 1)
void gru_mfma(const float* __restrict__ in_data, const float* __restrict__ hidden,
              const float* __restrict__ W_ih,   const float* __restrict__ W_hh,
              const float* __restrict__ b_ih,   const float* __restrict__ b_hh,
              const float* __restrict__ W_out,  const float* __restrict__ b_out,
              float* __restrict__ out, int B, int T)
{
    const float S_RZ = -1.44269504088896340736f;   // -log2(e)
    const float S_N  =  2.88539008177792681472f;   // 2*log2(e)

    const int lane = threadIdx.x & 63;
    const int n    = lane & 15;          // MFMA col within group; also A row
    const int g    = lane >> 4;          // k-group: B k-slice 8g..8g+7
    const int k0   = g * 8;
    const long eA  = (long)blockIdx.x * 32 + n;        // group A element
    const long eB  = eA + 16;                          // group B element

    // permuted weight-row mapping (C rows 4g+r -> comps 8g+r / 8g+4+r):
    const int rlo = 8 * (n >> 2) + (n & 3);
    const int rhi = rlo + 4;

    // ---- biases in C layout, pre-scaled ----
    f32x4 bC[8];
    #pragma unroll
    for (int p = 0; p < 2; ++p) {
        #pragma unroll
        for (int r = 0; r < 4; ++r) {
            const int c = 8 * g + 4 * p + r;
            bC[0 + p][r] = S_RZ * (b_ih[c]      + b_hh[c]);       // r
            bC[2 + p][r] = S_RZ * (b_ih[32 + c] + b_hh[32 + c]);  // z
            bC[4 + p][r] = S_N  *  b_ih[64 + c];                  // i_n
            bC[6 + p][r] = S_N  *  b_hh[64 + c];                  // h_n
        }
    }
    float wl[4], wh[4];
    #pragma unroll
    for (int r = 0; r < 4; ++r) { wl[r] = W_out[8*g + r]; wh[r] = W_out[8*g + 4 + r]; }
    const float boutv = b_out[0];
    float* const opA = out + eA * (long)T;
    float* const opB = out + eB * (long)T;

    // ---- initial h and x fragments for both groups ----
    float hpA[8], hpB[8];
    F3 BvA, BvB, BxA, BxB;
    {
        float f[8];
        ldrow8(hidden + eA * 32 + k0, f);
        #pragma unroll
        for (int i = 0; i < 8; ++i) hpA[i] = f[i];
        BvA = split8(f);
        ldrow8(hidden + eB * 32 + k0, f);
        #pragma unroll
        for (int i = 0; i < 8; ++i) hpB[i] = f[i];
        BvB = split8(f);
        ldrow8(in_data + eA * 32 + k0, f); BxA = split8(f);
        ldrow8(in_data + eB * 32 + k0, f); BxB = split8(f);
    }

    F3 A[8];
    f32x4 CA[8], CB[8];

    // ---- step 0, x-phase: scaled W_ih tiles {r,z,n} x {lo,hi} ----
    #pragma unroll
    for (int gs = 0; gs < 3; ++gs) {
        const float s = (gs < 2) ? S_RZ : S_N;
        float fl[8], fh[8];
        ldrow8s(W_ih + (gs * 32 + rlo) * 32 + k0, fl, s);
        ldrow8s(W_ih + (gs * 32 + rhi) * 32 + k0, fh, s);
        A[2*gs] = split8(fl); A[2*gs+1] = split8(fh);
    }
    #pragma unroll
    for (int rt = 0; rt < 6; ++rt) { CA[rt] = mm6(A[rt], BxA, bC[rt]);
                                     CB[rt] = mm6(A[rt], BxB, bC[rt]); }

    // ---- step 0, h-phase: scaled W_hh; r,z accumulate; h_n -> C6,C7 ----
    #pragma unroll
    for (int gs = 0; gs < 3; ++gs) {
        const float s = (gs < 2) ? S_RZ : S_N;
        float fl[8], fh[8];
        ldrow8s(W_hh + (gs * 32 + rlo) * 32 + k0, fl, s);
        ldrow8s(W_hh + (gs * 32 + rhi) * 32 + k0, fh, s);
        A[2*gs] = split8(fl); A[2*gs+1] = split8(fh);
    }
    #pragma unroll
    for (int rt = 0; rt < 4; ++rt) { CA[rt] = mm6(A[rt], BvA, CA[rt]);
                                     CB[rt] = mm6(A[rt], BvB, CB[rt]); }
    CA[6] = mm6(A[4], BvA, bC[6]);  CB[6] = mm6(A[4], BvB, bC[6]);
    CA[7] = mm6(A[5], BvA, bC[7]);  CB[7] = mm6(A[5], BvB, bC[7]);

    // ---- fused weights for t>=1 (x==h): r,z = s*(Wih+Whh); i_n; h_n ----
    #pragma unroll
    for (int gs = 0; gs < 2; ++gs) {
        float fl[8], fh[8], g2[8];
        ldrow8(W_ih + (gs * 32 + rlo) * 32 + k0, fl);
        ldrow8(W_hh + (gs * 32 + rlo) * 32 + k0, g2);
        #pragma unroll
        for (int i = 0; i < 8; ++i) fl[i] = S_RZ * (fl[i] + g2[i]);
        ldrow8(W_ih + (gs * 32 + rhi) * 32 + k0, fh);
        ldrow8(W_hh + (gs * 32 + rhi) * 32 + k0, g2);
        #pragma unroll
        for (int i = 0; i < 8; ++i) fh[i] = S_RZ * (fh[i] + g2[i]);
        A[2*gs] = split8(fl); A[2*gs+1] = split8(fh);
    }
    {
        float fl[8], fh[8];
        ldrow8s(W_ih + (64 + rlo) * 32 + k0, fl, S_N);
        ldrow8s(W_ih + (64 + rhi) * 32 + k0, fh, S_N);
        A[4] = split8(fl); A[5] = split8(fh);
        ldrow8s(W_hh + (64 + rlo) * 32 + k0, fl, S_N);
        ldrow8s(W_hh + (64 + rhi) * 32 + k0, fh, S_N);
        A[6] = split8(fl); A[7] = split8(fh);
    }

    const bool st = (lane < 16);

    // ---- rotated pipeline: prologue combineA(0) ----
    combineG(CA, hpA, BvA, wl, wh, boutv, opA, 0, st);

    // body t: MFMA_A -> CA(t+1) ; combineB(t) ; MFMA_B -> CB(t+1) ; combineA(t+1)
    // Each MFMA burst is adjacent to an independent combine -> interleavable.
    #pragma unroll 1
    for (int t = 0; t < T - 1; ++t) {
        mfma8(A, BvA, bC, CA);
        combineG(CB, hpB, BvB, wl, wh, boutv, opB, t, st);
        mfma8(A, BvB, bC, CB);
        combineG(CA, hpA, BvA, wl, wh, boutv, opA, t + 1, st);
    }

    // epilogue: combineB(T-1)
    combineG(CB, hpB, BvB, wl, wh, boutv, opB, T - 1, st);
}

extern "C" void kernel_launch(void* const* d_in, const int* in_sizes, int n_in,
                              void* d_out, int out_size, void* d_ws, size_t ws_size,
                              hipStream_t stream) {
    const float* in_data = (const float*)d_in[0];
    const float* hidden  = (const float*)d_in[1];
    const float* W_ih    = (const float*)d_in[2];
    const float* W_hh    = (const float*)d_in[3];
    const float* b_ih    = (const float*)d_in[4];
    const float* b_hh    = (const float*)d_in[5];
    const float* W_out   = (const float*)d_in[6];
    const float* b_out   = (const float*)d_in[7];
    float* out = (float*)d_out;

    const int B = in_sizes[0] / 32;       // 32768
    const int T = out_size / B;           // 128
    const int blocks = B / 32;            // 32 elems per 64-thread (1-wave) block

    gru_mfma<<<blocks, 64, 0, stream>>>(in_data, hidden, W_ih, W_hh,
                                        b_ih, b_hh, W_out, b_out, out, B, T);
}